// Round 4
// baseline (63.474 us; speedup 1.0000x reference)
//
#include <hip/hip_runtime.h>

// Gated CRF 3D->2D loss, round 10: warm-up streamer before the gather.
// Evidence: crf FETCH_SIZE = 5.26 MB/dispatch (round-8 profile) vs 4 MiB
// of live input -> the harness's 268 MB poison-fill evicts L2+MALL every
// iteration and the gather starts HBM-cold, stalled ~12us on scattered
// miss handling (MSHR-limited: ILP x6 (r7) and L2-slab locality (r9)
// both nulled). Fix: a dense streaming toucher reads all 4 MiB at
// copy-BW into L2 (slab-matched to the gather's XCD mapping, loads kept
// live via asm, no stores), so crf_partial runs L2-warm.

constexpr int N = 2, H = 64, W = 64, D = 64, R = 3;
constexpr int WD  = W * D;
constexpr int HWD = H * W * D;
constexpr float INV_SXY  = 1.0f / 6.0f;
constexpr float LOG2E    = 1.4426950408889634f;
constexpr float C2       = 50.0f * LOG2E;   // 0.5*(1/0.1)^2 * log2(e)
constexpr int GBLOCKS = N * H * (W / 16);   // 512 spatial blocks
constexpr int NBLOCKS = 4 * GBLOCKS;        // x4 offset groups = 2048

__device__ __forceinline__ float exp2_fast(float x) {
    return __builtin_amdgcn_exp2f(x);       // v_exp_f32
}

// ---------------------------------------------------------------------------
// Warm-up streamer: 512 blocks x 256 threads, each thread one float4 from
// y(ch0) and s. Covers every cache line of the live input exactly once.
// xcd = bid & 7 owns h-slab [8*xcd, 8*xcd+8) -- same mapping as crf_partial,
// so each XCD L2 is warmed with the slab its gather blocks will read.
__global__ __launch_bounds__(256) void touch_inputs(
    const float* __restrict__ y, const float* __restrict__ s) {
    const int bid   = blockIdx.x;
    const int xcd   = bid & 7;
    const int r     = bid >> 3;           // 0..63 within XCD
    const int h_loc = r & 7;
    const int wstrip= (r >> 3) & 3;
    const int n     = r >> 5;
    const int h     = (xcd << 3) + h_loc;
    const int t     = threadIdx.x;
    const int w     = (wstrip << 4) + (t >> 4);
    const int d0    = (t & 15) << 2;
    const int idx   = h * WD + w * D + d0;

    const float4 a = *(const float4*)(y + (size_t)n * (2 * HWD) + idx);
    const float4 b = *(const float4*)(s + (size_t)n * HWD + idx);
    // Keep loads live without storing (rule #17).
    asm volatile("" :: "v"(a.x), "v"(a.y), "v"(a.z), "v"(a.w));
    asm volatile("" :: "v"(b.x), "v"(b.y), "v"(b.z), "v"(b.w));
}
// ---------------------------------------------------------------------------

// One offset group: 6 pairs, fully unrolled, loads batched before compute.
template <int DI0, int DJ0, int DI1, int DJ1, int DI2, int DJ2,
          int DI3, int DJ3, int DI4, int DJ4, int DI5, int DJ5>
__device__ __forceinline__ float group_sum(
    const float* __restrict__ sb, const float* __restrict__ y0b,
    int cidx, int h, int w,
    const float scv[4], const float bv[4]) {
    constexpr int DI[6] = {DI0, DI1, DI2, DI3, DI4, DI5};
    constexpr int DJ[6] = {DJ0, DJ1, DJ2, DJ3, DJ4, DJ5};

    bool   vld[6];
    float4 sn[6], an[6];

    #pragma unroll
    for (int p = 0; p < 6; ++p) {
        const bool v = ((unsigned)(h + DI[p]) < (unsigned)H) &
                       ((unsigned)(w + DJ[p]) < (unsigned)W);
        vld[p] = v;
        const int off = v ? (DI[p] * WD + DJ[p] * D) : 0;  // clamp -> center
        sn[p] = *(const float4*)(sb  + cidx + off);
        an[p] = *(const float4*)(y0b + cidx + off);
    }

    float acc = 0.0f;
    #pragma unroll
    for (int p = 0; p < 6; ++p) {
        constexpr float d2[6] = {
            (float)(DI0 * DI0 + DJ0 * DJ0), (float)(DI1 * DI1 + DJ1 * DJ1),
            (float)(DI2 * DI2 + DJ2 * DJ2), (float)(DI3 * DI3 + DJ3 * DJ3),
            (float)(DI4 * DI4 + DJ4 * DJ4), (float)(DI5 * DI5 + DJ5 * DJ5)};
        const float A2  = -0.5f * d2[p] * (INV_SXY * INV_SXY) * LOG2E;
        const float A2e = vld[p] ? A2 : -1e30f;
        const float snv[4] = {sn[p].x, sn[p].y, sn[p].z, sn[p].w};
        const float anv[4] = {an[p].x, an[p].y, an[p].z, an[p].w};
        #pragma unroll
        for (int j = 0; j < 4; ++j) {
            const float dsr = snv[j] - scv[j];
            const float k   = exp2_fast(__builtin_fmaf(-C2 * dsr, dsr, A2e));
            const float ab  = anv[j] * bv[j];
            acc += k * (anv[j] + bv[j] - 2.0f * ab);
        }
    }
    return acc;
}

__global__ __launch_bounds__(256) void crf_partial(
    const float* __restrict__ y,   // (N,2,H,W,D) -- only channel 0 read
    const float* __restrict__ s,   // (N,1,H,W,D)
    float* __restrict__ partial) {
    const int tid   = threadIdx.x;
    const int d0    = (tid & 15) << 2;
    const int wlane = tid >> 4;
    const int bid   = blockIdx.x;

    // XCD-slab remap (kept from round 9; matches the toucher's mapping).
    const int xcd    = bid & 7;
    const int r      = bid >> 3;          // 0..255 within XCD
    const int g      = r & 3;             // offset group 0..3
    const int wstrip = (r >> 2) & 3;
    const int h_loc  = (r >> 4) & 7;
    const int n      = r >> 7;
    const int h      = (xcd << 3) + h_loc;
    const int w      = (wstrip << 4) + wlane;
    // Canonical (round-7) partial index: reduce order stays bitwise-equal.
    const int pidx   = (g << 9) | (n << 8) | (h << 2) | wstrip;

    const float* sb  = s + (size_t)n * HWD;
    const float* y0b = y + (size_t)n * (2 * HWD);

    const int cidx = h * WD + w * D + d0;
    const float4 sc4 = *(const float4*)(sb  + cidx);
    const float4 b4  = *(const float4*)(y0b + cidx);
    const float scv[4] = {sc4.x, sc4.y, sc4.z, sc4.w};
    const float bv[4]  = {b4.x,  b4.y,  b4.z,  b4.w};

    float acc = 0.0f;
    float extra = 0.0f;
    if (g == 0) {
        acc = group_sum<0, 1, 0, 2, 0, 3, 1, -3, 1, -2, 1, -1>(
            sb, y0b, cidx, h, w, scv, bv);
        // OOB closed form (window truncation), group 0 only.
        const int nrows = min(h + R, H - 1) - max(h - R, 0) + 1;
        const int ncols = min(w + R, W - 1) - max(w - R, 0) + 1;
        const int oob = 49 - nrows * ncols;
        if (oob) {
            const float fh = (float)h * INV_SXY;
            const float fw = (float)w * INV_SXY;
            const float base2 = -0.5f * (fh * fh + fw * fw) * LOG2E;
            float koob = 0.0f;
            #pragma unroll
            for (int j = 0; j < 4; ++j)
                koob += exp2_fast(__builtin_fmaf(-C2 * scv[j], scv[j], base2));
            extra = (float)oob * koob;
        }
    } else if (g == 1) {
        acc = group_sum<1, 0, 1, 1, 1, 2, 1, 3, 2, -3, 2, -2>(
            sb, y0b, cidx, h, w, scv, bv);
    } else if (g == 2) {
        acc = group_sum<2, -1, 2, 0, 2, 1, 2, 2, 2, 3, 3, -3>(
            sb, y0b, cidx, h, w, scv, bv);
    } else {
        acc = group_sum<3, -2, 3, -1, 3, 0, 3, 1, 3, 2, 3, 3>(
            sb, y0b, cidx, h, w, scv, bv);
    }

    float part = 2.0f * acc + extra;

    #pragma unroll
    for (int off = 32; off; off >>= 1)
        part += __shfl_down(part, off, 64);

    __shared__ float wsum[4];
    if ((tid & 63) == 0) wsum[tid >> 6] = part;
    __syncthreads();
    if (tid == 0) partial[pidx] = wsum[0] + wsum[1] + wsum[2] + wsum[3];
}

__global__ __launch_bounds__(256) void reduce_partials(
    const float* __restrict__ partial, float* __restrict__ out) {
    const int tid = threadIdx.x;
    float v = 0.0f;
    #pragma unroll
    for (int i = 0; i < NBLOCKS / 256; ++i)
        v += partial[tid + i * 256];
    #pragma unroll
    for (int off = 32; off; off >>= 1)
        v += __shfl_down(v, off, 64);
    __shared__ float wsum[4];
    if ((tid & 63) == 0) wsum[tid >> 6] = v;
    __syncthreads();
    if (tid == 0)
        out[0] = (wsum[0] + wsum[1] + wsum[2] + wsum[3]) *
                 (1.0f / (float)(N * D * H * W));
}

extern "C" void kernel_launch(void* const* d_in, const int* in_sizes, int n_in,
                              void* d_out, int out_size, void* d_ws, size_t ws_size,
                              hipStream_t stream) {
    const float* y = (const float*)d_in[0];
    const float* s = (const float*)d_in[1];
    float* partial = (float*)d_ws;   // NBLOCKS floats, all written before read

    touch_inputs<<<dim3(GBLOCKS), dim3(256), 0, stream>>>(y, s);
    crf_partial<<<dim3(NBLOCKS), dim3(256), 0, stream>>>(y, s, partial);
    reduce_partials<<<dim3(1), dim3(256), 0, stream>>>(partial, (float*)d_out);
}

// Round 6
// 62.202 us; speedup vs baseline: 1.0204x; 1.0204x over previous
//
#include <hip/hip_runtime.h>

// Gated CRF 3D->2D loss, round 11b: LDS-staged tile, merged offset groups.
// (Resubmit of round 11 -- previous bench died on container infra, no
// kernel verdict. Source audited: no hang paths, all indices in bounds.)
// Ledger: r7 (MLP x6) null, r9 (XCD slab) null, r10 (L2 pre-warm) null
// -> gather is bound by the per-CU L1<->L2 path: 8 blocks/CU share a
// ~456 KB working set against 32 KiB L1, so ALL 14 loads/thread miss L1
// (~12 B/cy/CU effective). Fix: stage through LDS.
// Pair symmetry => all 24 offsets have di>=0 => a block only needs rows
// h..h+3: tile [4][64][16] x {s, y0} = 32 KB LDS, staged by 8 dense
// coalesced float4 loads/thread. All 4 offset groups merged into one
// block: 512 blocks = n(2) x h(64) x dq(4). Gather becomes ds_read_b128
// (wave reads 1 KB contiguous: conflict-free). Global traffic 117->17 MB.
// XCD-slab bid mapping: xcd owns an 8-row h-slab -> per-XCD staging
// fetch stays near-compulsory (~6 MB chip-wide).

constexpr int N = 2, H = 64, W = 64, D = 64, R = 3;
constexpr int WD  = W * D;
constexpr int HWD = H * W * D;
constexpr float INV_SXY  = 1.0f / 6.0f;
constexpr float LOG2E    = 1.4426950408889634f;
constexpr float C2       = 50.0f * LOG2E;   // 0.5*(1/0.1)^2 * log2(e)
constexpr int NBLOCKS = 2 * 64 * 4;         // n x h x dq = 512

__device__ __forceinline__ float exp2_fast(float x) {
    return __builtin_amdgcn_exp2f(x);       // v_exp_f32
}

// One offset group: 6 pairs, LDS-sourced, loads batched before compute.
// Tile layout: sT/yT[di][w][dd] = [4][64][16] floats, di = row offset 0..3.
template <int DI0, int DJ0, int DI1, int DJ1, int DI2, int DJ2,
          int DI3, int DJ3, int DI4, int DJ4, int DI5, int DJ5>
__device__ __forceinline__ float group_sum_lds(
    const float* __restrict__ sT, const float* __restrict__ yT,
    int w, int doff, int h, const float scv[4], const float bv[4]) {
    constexpr int DI[6] = {DI0, DI1, DI2, DI3, DI4, DI5};
    constexpr int DJ[6] = {DJ0, DJ1, DJ2, DJ3, DJ4, DJ5};

    bool   vld[6];
    float4 sn[6], an[6];

    // Phase 1: all 12 ds_read_b128 batched.
    #pragma unroll
    for (int p = 0; p < 6; ++p) {
        vld[p] = (h + DI[p] < H) &
                 ((unsigned)(w + DJ[p]) < (unsigned)W);
        const int wcl = min(max(w + DJ[p], 0), W - 1);
        const int off = (DI[p] * W + wcl) * 16 + doff;
        sn[p] = *(const float4*)(sT + off);
        an[p] = *(const float4*)(yT + off);
    }

    // Phase 2: compute. Invalid pairs get A2 = -1e30 -> exp2 -> 0.
    float acc = 0.0f;
    #pragma unroll
    for (int p = 0; p < 6; ++p) {
        constexpr float d2[6] = {
            (float)(DI0 * DI0 + DJ0 * DJ0), (float)(DI1 * DI1 + DJ1 * DJ1),
            (float)(DI2 * DI2 + DJ2 * DJ2), (float)(DI3 * DI3 + DJ3 * DJ3),
            (float)(DI4 * DI4 + DJ4 * DJ4), (float)(DI5 * DI5 + DJ5 * DJ5)};
        const float A2  = -0.5f * d2[p] * (INV_SXY * INV_SXY) * LOG2E;
        const float A2e = vld[p] ? A2 : -1e30f;
        const float snv[4] = {sn[p].x, sn[p].y, sn[p].z, sn[p].w};
        const float anv[4] = {an[p].x, an[p].y, an[p].z, an[p].w};
        #pragma unroll
        for (int j = 0; j < 4; ++j) {
            const float dsr = snv[j] - scv[j];
            const float k   = exp2_fast(__builtin_fmaf(-C2 * dsr, dsr, A2e));
            const float ab  = anv[j] * bv[j];
            acc += k * (anv[j] + bv[j] - 2.0f * ab);
        }
    }
    return acc;
}

__global__ __launch_bounds__(256) void crf_partial(
    const float* __restrict__ y,   // (N,2,H,W,D) -- only channel 0 read
    const float* __restrict__ s,   // (N,1,H,W,D)
    float* __restrict__ partial) {
    const int tid = threadIdx.x;
    const int bid = blockIdx.x;

    // XCD-slab remap: xcd (= bid&7, dispatch round-robin) owns h-slab
    // [8*xcd, 8*xcd+8), all dq and both n -> staging stays L2-local.
    const int xcd = bid & 7;
    const int q   = bid >> 3;             // 0..63
    const int h   = (xcd << 3) | (q & 7);
    const int dq  = (q >> 3) & 3;         // d-quarter 0..3
    const int n   = q >> 5;
    const int pidx = ((n << 6) + h) * 4 + dq;  // canonical partial index
    const int d0b  = dq << 4;             // base d of this 16-float chunk

    const float* sb  = s + (size_t)n * HWD;
    const float* y0b = y + (size_t)n * (2 * HWD);

    // --- Stage tile rows h..h+3 (clamped), full W, 16 d-floats ---------
    __shared__ float sT[4 * 64 * 16];     // 16 KB
    __shared__ float yT[4 * 64 * 16];     // 16 KB
    #pragma unroll
    for (int c = 0; c < 4; ++c) {
        const int fidx = (c << 10) + (tid << 2);   // float index in tile
        const int wg   = (fidx >> 4) & 63;
        const int dd   = fidx & 15;                // 0,4,8,12
        const int hh   = min(h + c, H - 1);        // clamp; masked later
        const int gidx = hh * WD + wg * D + d0b + dd;
        *(float4*)(sT + fidx) = *(const float4*)(sb  + gidx);
        *(float4*)(yT + fidx) = *(const float4*)(y0b + gidx);
    }
    __syncthreads();
    // -------------------------------------------------------------------

    const int w    = tid >> 2;            // 0..63
    const int doff = (tid & 3) << 2;      // 0,4,8,12 (float offset in chunk)

    const float4 sc4 = *(const float4*)(sT + w * 16 + doff);
    const float4 b4  = *(const float4*)(yT + w * 16 + doff);
    const float scv[4] = {sc4.x, sc4.y, sc4.z, sc4.w};
    const float bv[4]  = {b4.x,  b4.y,  b4.z,  b4.w};

    // All 24 symmetric pair offsets (di>=0), in the round-6 group order.
    float acc = 0.0f;
    acc += group_sum_lds<0, 1, 0, 2, 0, 3, 1, -3, 1, -2, 1, -1>(
        sT, yT, w, doff, h, scv, bv);
    acc += group_sum_lds<1, 0, 1, 1, 1, 2, 1, 3, 2, -3, 2, -2>(
        sT, yT, w, doff, h, scv, bv);
    acc += group_sum_lds<2, -1, 2, 0, 2, 1, 2, 2, 2, 3, 3, -3>(
        sT, yT, w, doff, h, scv, bv);
    acc += group_sum_lds<3, -2, 3, -1, 3, 0, 3, 1, 3, 2, 3, 3>(
        sT, yT, w, doff, h, scv, bv);

    // OOB closed form (window truncation), once per (h,w,d) site.
    float extra = 0.0f;
    {
        const int nrows = min(h + R, H - 1) - max(h - R, 0) + 1;
        const int ncols = min(w + R, W - 1) - max(w - R, 0) + 1;
        const int oob = 49 - nrows * ncols;
        if (oob) {
            const float fh = (float)h * INV_SXY;
            const float fw = (float)w * INV_SXY;
            const float base2 = -0.5f * (fh * fh + fw * fw) * LOG2E;
            float koob = 0.0f;
            #pragma unroll
            for (int j = 0; j < 4; ++j)
                koob += exp2_fast(__builtin_fmaf(-C2 * scv[j], scv[j], base2));
            extra = (float)oob * koob;
        }
    }

    float part = 2.0f * acc + extra;

    #pragma unroll
    for (int off = 32; off; off >>= 1)
        part += __shfl_down(part, off, 64);

    __shared__ float wsum[4];
    if ((tid & 63) == 0) wsum[tid >> 6] = part;
    __syncthreads();
    if (tid == 0) partial[pidx] = wsum[0] + wsum[1] + wsum[2] + wsum[3];
}

__global__ __launch_bounds__(256) void reduce_partials(
    const float* __restrict__ partial, float* __restrict__ out) {
    const int tid = threadIdx.x;
    float v = 0.0f;
    #pragma unroll
    for (int i = 0; i < NBLOCKS / 256; ++i)
        v += partial[tid + i * 256];
    #pragma unroll
    for (int off = 32; off; off >>= 1)
        v += __shfl_down(v, off, 64);
    __shared__ float wsum[4];
    if ((tid & 63) == 0) wsum[tid >> 6] = v;
    __syncthreads();
    if (tid == 0)
        out[0] = (wsum[0] + wsum[1] + wsum[2] + wsum[3]) *
                 (1.0f / (float)(N * D * H * W));
}

extern "C" void kernel_launch(void* const* d_in, const int* in_sizes, int n_in,
                              void* d_out, int out_size, void* d_ws, size_t ws_size,
                              hipStream_t stream) {
    const float* y = (const float*)d_in[0];
    const float* s = (const float*)d_in[1];
    float* partial = (float*)d_ws;   // NBLOCKS floats, all written before read

    crf_partial<<<dim3(NBLOCKS), dim3(256), 0, stream>>>(y, s, partial);
    reduce_partials<<<dim3(1), dim3(256), 0, stream>>>(partial, (float*)d_out);
}